// Round 16
// baseline (2280.461 us; speedup 1.0000x reference)
//
#include <hip/hip_runtime.h>
#include <hip/hip_bf16.h>

// RNNModule: leaky ReLU RNN scan + output projection, MI355X (gfx950).
// r16: r15 with the compile fix (native ext_vector float2 for the NT partial
//      store). r12 scan (spill-free breg 46 + 18 LDS frags, 160KB LDS, two
//      lgkm-only barriers, b16 h-writes) + FUSED output projection: per-step
//      32 FMA/lane vs w_out register slice, circular-DPP row reduce (VALU pipe,
//      in the LDS-write shadow), lr==0 lanes store per-wave partials; trailing
//      reduce kernel sums 8 wave planes. Fallback to unfused r12 if ws small.

typedef __attribute__((ext_vector_type(4))) float f32x4;
typedef __attribute__((ext_vector_type(2))) float f32x2;
typedef __attribute__((ext_vector_type(8))) short s16x8;

constexpr int BB = 256, TT = 750, NN = 512, INN = 6, OUTN = 2, MLEN = 250;
constexpr int BBLK = 16;                 // batch rows per block
constexpr int NBLKS = BB / BBLK;         // 16 blocks, one per CU
constexpr int WPB = 8;                   // waves per block
constexpr int NSL = NN / WPB;            // 64 neurons per wave
constexpr int NREG = 46;                 // B-frags in registers (f=0..45)
constexpr int NLDSF = 18;                // B-frags in LDS (f=46..63)
constexpr int HBYTES = BBLK * NN * 2;    // 16 KB h tile (bf16, swizzled)
constexpr int WOFF = HBYTES;             // weights region start
constexpr int SMEM_BYTES = WOFF + WPB * NLDSF * 1024;  // 163840 B = 160 KB
constexpr int DRVELTS = NBLKS * WPB * 64 * 16;         // shorts per time step
constexpr size_t DRVTOT = (size_t)(TT - 1) * DRVELTS;  // shorts in drive buffer
constexpr size_t PARTN = (size_t)WPB * BB * TT * OUTN; // per-wave proj partials

__device__ __forceinline__ unsigned short f2bf(float f) {
    unsigned v = __float_as_uint(f);
    v += 0x7fffu + ((v >> 16) & 1u);     // RNE
    return (unsigned short)(v >> 16);
}
__device__ __forceinline__ float bf2f(unsigned short h) {
    return __uint_as_float(((unsigned)h) << 16);
}

// circular rotate-accumulate over the 16-lane row: every lane ends with row sum
#define DPPRED(v)                                                                 \
    v += __int_as_float(__builtin_amdgcn_mov_dpp(__float_as_int(v), 0x128, 0xF, 0xF, false)); \
    v += __int_as_float(__builtin_amdgcn_mov_dpp(__float_as_int(v), 0x124, 0xF, 0xF, false)); \
    v += __int_as_float(__builtin_amdgcn_mov_dpp(__float_as_int(v), 0x122, 0xF, 0xF, false)); \
    v += __int_as_float(__builtin_amdgcn_mov_dpp(__float_as_int(v), 0x121, 0xF, 0xF, false));

// ---- pre-pass: drv[t][blk][wave][lane][16] bf16 = noise + u @ w_in^T ----
__global__ __launch_bounds__(256)
void drive_kernel(const float* __restrict__ u, const float* __restrict__ noise,
                  const float* __restrict__ w_in, unsigned short* __restrict__ drv)
{
    int gid = blockIdx.x * 256 + threadIdx.x;
    int t = gid >> 13;                           // 16 blk * 8 w * 64 lanes = 8192
    if (t >= TT - 1) return;
    int lane = gid & 63, w = (gid >> 6) & 7, blk = (gid >> 9) & 15;
    int qq = lane >> 4, lr = lane & 15;

    float wv[4][INN];
    #pragma unroll
    for (int tt = 0; tt < 4; ++tt) {
        int n = w * NSL + 16 * tt + lr;
        #pragma unroll
        for (int i = 0; i < INN; ++i) wv[tt][i] = w_in[n * INN + i];
    }
    alignas(16) unsigned short o[16];
    #pragma unroll
    for (int r = 0; r < 4; ++r) {
        int b = blk * BBLK + 4 * qq + r;
        const float* up = u + ((size_t)b * TT + t) * INN;
        float uv[INN];
        #pragma unroll
        for (int i = 0; i < INN; ++i) uv[i] = up[i];
        const float* np = noise + ((size_t)b * TT + t) * NN;
        #pragma unroll
        for (int tt = 0; tt < 4; ++tt) {
            int n = w * NSL + 16 * tt + lr;
            float d = np[n];
            #pragma unroll
            for (int i = 0; i < INN; ++i) d += uv[i] * wv[tt][i];
            o[tt * 4 + r] = f2bf(d);
        }
    }
    s16x8* dst = (s16x8*)(drv + (size_t)gid * 16);
    dst[0] = *(const s16x8*)&o[0];
    dst[1] = *(const s16x8*)&o[8];
}

// ---- persistent scan: 16 blocks x 8 waves, LDS-only h exchange ----
template<bool FUSE>
__global__ __launch_bounds__(512, 2)
void rnn_scan_kernel(const float* __restrict__ w_rec,
                     const unsigned short* __restrict__ drv,
                     const float* __restrict__ w_out,
                     float* __restrict__ states, float* __restrict__ part)
{
    extern __shared__ char smem[];
    const int tid = threadIdx.x;
    const int w = tid >> 6, lane = tid & 63;
    const int qq = lane >> 4, lr = lane & 15, p7 = lr & 7;
    const int blk = blockIdx.x;
    const int bg = blk * BBLK;

    // stage weights: frag f=tt*16+kk: lane holds w_rec[n=64w+16tt+lr][32kk+8qq+j]
    // f < 46 -> registers; f >= 46 -> LDS slot f-46
    s16x8 breg[NREG];
    #pragma unroll
    for (int tt = 0; tt < 4; ++tt) {
        #pragma unroll
        for (int kk = 0; kk < 16; ++kk) {
            const int f = tt * 16 + kk;
            const int n = w * NSL + 16 * tt + lr;
            const float* p = w_rec + (size_t)n * NN + 32 * kk + 8 * qq;
            f32x4 x0 = *(const f32x4*)p;
            f32x4 x1 = *(const f32x4*)(p + 4);
            union { s16x8 v; unsigned short s[8]; } fr;
            #pragma unroll
            for (int j = 0; j < 4; ++j) { fr.s[j] = f2bf(x0[j]); fr.s[4+j] = f2bf(x1[j]); }
            if (f < NREG) breg[f] = fr.v;
            else *(s16x8*)(smem + WOFF + (w * NLDSF + (f - NREG)) * 1024 + lane * 16) = fr.v;
        }
    }
    // w_out slice: wo[tt*2+o] = w_out[o][w*64+16tt+lr]
    float wo[8];
    if (FUSE) {
        #pragma unroll
        for (int tt = 0; tt < 4; ++tt) {
            int n = w * NSL + 16 * tt + lr;
            wo[tt * 2]     = w_out[n];
            wo[tt * 2 + 1] = w_out[NN + n];
        }
    }
    // zero h buffer (h_0 = 0) and states[:,0,:] for our rows
    for (int i = tid; i < HBYTES / 4; i += 512) ((unsigned*)smem)[i] = 0u;
    for (int i = tid; i < BBLK * NN; i += 512)
        states[(size_t)(bg + (i >> 9)) * TT * NN + (i & 511)] = 0.f;
    __syncthreads();

    float stl[16];
    #pragma unroll
    for (int i = 0; i < 16; ++i) stl[i] = 0.f;

    // A-read folded bases: addr(kk) = lr*1024 + ((4kk+qq)^p7)<<4 = base(E/O) + 64kk
    const int rb64 = (p7 & 4) << 4;
    const int hbase0 = lr * 1024 + ((qq ^ (p7 & 3)) << 4);
    const char* hbE = smem + hbase0 + rb64;
    const char* hbO = smem + hbase0 - rb64;
    const char* wbase = smem + WOFF + w * (NLDSF * 1024) + lane * 16;

    // h-write folded base: addr(tt,r) = (LB ^ (((2tt)^r)<<4)) + 1024r
    const int s0 = 8 * w + (lr >> 3);
    const unsigned LB = 4096u * qq + ((unsigned)(s0 ^ (4 * (qq & 1))) << 4) + 2 * (lr & 7);

    float* rowp[4];
    #pragma unroll
    for (int r = 0; r < 4; ++r)
        rowp[r] = states + ((size_t)(bg + 4 * qq + r) * TT + 1) * NN + w * NSL + lr;

    // proj partials pointer: part[((w*256 + b)*750 + t)*2 + o], b = bg+4qq+r
    float* ppart = part + (((size_t)w * BB + bg + 4 * qq) * TT + 1) * OUTN;

    const unsigned short* dptr = drv + ((size_t)(blk * WPB + w) * 64 + lane) * 16;

    for (int s = 1; s < TT; ++s) {
        // depth-0 drive load: consumed ~2500 cyc later in the epilogue
        const s16x8* dp = (const s16x8*)dptr;
        s16x8 dv0 = dp[0], dv1 = dp[1];
        dptr += DRVELTS;

        f32x4 a0 = {0.f,0.f,0.f,0.f}, a1 = a0, a2 = a0, a3 = a0;
        #pragma unroll
        for (int kk = 0; kk < 16; ++kk) {
            s16x8 av = *(const s16x8*)(((kk & 1) ? hbO : hbE) + (kk << 6));
            a0 = __builtin_amdgcn_mfma_f32_16x16x32_bf16(av, breg[kk],      a0, 0,0,0);
            a1 = __builtin_amdgcn_mfma_f32_16x16x32_bf16(av, breg[16 + kk], a1, 0,0,0);
            if (kk < 14)
                a2 = __builtin_amdgcn_mfma_f32_16x16x32_bf16(av, breg[32+kk], a2, 0,0,0);
            else
                a2 = __builtin_amdgcn_mfma_f32_16x16x32_bf16(
                         av, *(const s16x8*)(wbase + ((kk - 14) << 10)), a2, 0, 0, 0);
            a3 = __builtin_amdgcn_mfma_f32_16x16x32_bf16(
                     av, *(const s16x8*)(wbase + ((2 + kk) << 10)), a3, 0, 0, 0);
        }

        // ---- epilogue compute (incl. fused proj partials) BEFORE barrier 1;
        //      only the LDS h-writes must wait for it ----
        union { s16x8 v; unsigned short e[8]; } U0, U1;
        U0.v = dv0; U1.v = dv1;
        const f32x4 aX[4] = {a0, a1, a2, a3};
        unsigned pk[8];
        float po[8];
        #pragma unroll
        for (int i = 0; i < 8; ++i) po[i] = 0.f;
        #pragma unroll
        for (int p = 0; p < 2; ++p) {
            #pragma unroll
            for (int r = 0; r < 4; ++r) {
                float dE = bf2f(p == 0 ? U0.e[r]     : U1.e[r]);
                float dO = bf2f(p == 0 ? U0.e[4 + r] : U1.e[4 + r]);
                float hE = 0.8f * stl[(2*p)*4 + r]   + 0.2f * fmaxf(aX[2*p][r]   + dE, 0.f);
                float hO = 0.8f * stl[(2*p+1)*4 + r] + 0.2f * fmaxf(aX[2*p+1][r] + dO, 0.f);
                stl[(2*p)*4 + r] = hE;
                stl[(2*p+1)*4 + r] = hO;
                __builtin_nontemporal_store(hE, rowp[r] + (2*p) * 16);
                __builtin_nontemporal_store(hO, rowp[r] + (2*p+1) * 16);
                __hip_bfloat162 h2 = __float22bfloat162_rn(make_float2(hE, hO));
                pk[p * 4 + r] = *reinterpret_cast<unsigned*>(&h2);
                if (FUSE) {
                    po[2*r]   += hE * wo[4*p]     + hO * wo[4*p + 2];  // o = 0
                    po[2*r+1] += hE * wo[4*p + 1] + hO * wo[4*p + 3];  // o = 1
                }
            }
        }
        #pragma unroll
        for (int r = 0; r < 4; ++r) rowp[r] += NN;

        // barrier 1: all waves' A-reads drained -> safe to overwrite h
        asm volatile("s_waitcnt lgkmcnt(0)\n\ts_barrier" ::: "memory");

        #pragma unroll
        for (int tt = 0; tt < 4; ++tt) {
            #pragma unroll
            for (int r = 0; r < 4; ++r) {
                const unsigned C = (unsigned)(((2 * tt) ^ r) << 4);
                unsigned short hv = (tt & 1) ? (unsigned short)(pk[(tt >> 1) * 4 + r] >> 16)
                                             : (unsigned short)(pk[(tt >> 1) * 4 + r]);
                *(unsigned short*)(smem + ((LB ^ C) + 1024 * r)) = hv;
            }
        }
        if (FUSE) {
            // circular DPP reduce over the 16 lr-lanes (VALU pipe; overlaps
            // other waves' LDS writes); lr==0 lanes hold b = bg+4qq+r rows
            #pragma unroll
            for (int i = 0; i < 8; ++i) { DPPRED(po[i]) }
            if (lr == 0) {
                #pragma unroll
                for (int r = 0; r < 4; ++r) {
                    f32x2 pr = {po[2*r], po[2*r+1]};
                    __builtin_nontemporal_store(pr, (f32x2*)(ppart + (size_t)r * TT * OUTN));
                }
            }
            ppart += OUTN;
        }
        // barrier 2: h writes visible -> next step may read
        asm volatile("s_waitcnt lgkmcnt(0)\n\ts_barrier" ::: "memory");
    }
}

// outf[b,t,o] = sum_w part[w][b][t][o]; t==0 -> 0 (h_0 = 0)
__global__ __launch_bounds__(256)
void reduce_kernel(const float* __restrict__ part, float* __restrict__ outf)
{
    int idx = blockIdx.x * 256 + threadIdx.x;      // [b][t][o]
    if (idx >= BB * TT * OUTN) return;
    float s = 0.f;
    if ((idx >> 1) % TT != 0) {
        #pragma unroll
        for (int w = 0; w < WPB; ++w) s += part[(size_t)w * BB * TT * OUTN + idx];
    }
    outf[idx] = s;
}

// fallback: out[b,t,o] = sum_n states[b,t,n] * w_out[o,n]; one wave per row
__global__ __launch_bounds__(256)
void proj_kernel(const float* __restrict__ states, const float* __restrict__ w_out,
                 float* __restrict__ outf)
{
    const int wv   = (blockIdx.x * blockDim.x + threadIdx.x) >> 6;
    const int lane = threadIdx.x & 63;
    const float* sp = states + (size_t)wv * NN + lane * 8;
    const float* w0 = w_out + lane * 8;
    const float* w1 = w_out + NN + lane * 8;
    float d0 = 0.f, d1 = 0.f;
    #pragma unroll
    for (int i = 0; i < 8; ++i) {
        float sv = sp[i];
        d0 += sv * w0[i];
        d1 += sv * w1[i];
    }
    #pragma unroll
    for (int off = 32; off > 0; off >>= 1) {
        d0 += __shfl_xor(d0, off);
        d1 += __shfl_xor(d1, off);
    }
    if (lane == 0) {
        outf[(size_t)wv * 2]     = d0;
        outf[(size_t)wv * 2 + 1] = d1;
    }
}

__global__ void mask_kernel(const int* __restrict__ mask, const float* __restrict__ outf,
                            float* __restrict__ outm)
{
    int idx = blockIdx.x * blockDim.x + threadIdx.x;
    if (idx >= BB * MLEN * OUTN) return;
    int o  = idx % OUTN;
    int jm = (idx / OUTN) % MLEN;
    int b  = idx / (OUTN * MLEN);
    int t  = mask[jm];
    outm[idx] = outf[((size_t)b * TT + t) * OUTN + o];
}

extern "C" void kernel_launch(void* const* d_in, const int* in_sizes, int n_in,
                              void* d_out, int out_size, void* d_ws, size_t ws_size,
                              hipStream_t stream)
{
    (void)in_sizes; (void)n_in; (void)out_size;
    const float* u     = (const float*)d_in[0];
    const float* noise = (const float*)d_in[1];
    const float* w_rec = (const float*)d_in[2];
    const float* w_in  = (const float*)d_in[3];
    const float* w_out = (const float*)d_in[4];
    const int*   mask  = (const int*)d_in[5];

    float* states = (float*)d_out;                          // [256][750][512]
    float* outm   = states + (size_t)BB * TT * NN;          // [256][250][2]
    float* outf   = outm + (size_t)BB * MLEN * OUTN;        // [256][750][2]

    unsigned short* drvpk = (unsigned short*)d_ws;          // 196.3 MB packed drive
    float* part = (float*)(drvpk + DRVTOT);                 // 12.3 MB proj partials
    const bool fuse = ws_size >= DRVTOT * 2 + PARTN * 4;

    (void)hipFuncSetAttribute((const void*)rnn_scan_kernel<true>,
                              hipFuncAttributeMaxDynamicSharedMemorySize, SMEM_BYTES);
    (void)hipFuncSetAttribute((const void*)rnn_scan_kernel<false>,
                              hipFuncAttributeMaxDynamicSharedMemorySize, SMEM_BYTES);

    drive_kernel<<<(TT - 1) * 32, 256, 0, stream>>>(u, noise, w_in, drvpk);
    if (fuse) {
        rnn_scan_kernel<true><<<NBLKS, 512, SMEM_BYTES, stream>>>(
            w_rec, drvpk, w_out, states, part);
        reduce_kernel<<<(BB * TT * OUTN + 255) / 256, 256, 0, stream>>>(part, outf);
    } else {
        rnn_scan_kernel<false><<<NBLKS, 512, SMEM_BYTES, stream>>>(
            w_rec, drvpk, w_out, states, part);
        proj_kernel<<<(BB * TT) / 4, 256, 0, stream>>>(states, w_out, outf);
    }
    mask_kernel<<<(BB * MLEN * OUTN + 255) / 256, 256, 0, stream>>>(mask, outf, outm);
}

// Round 17
// 1966.714 us; speedup vs baseline: 1.1595x; 1.1595x over previous
//
#include <hip/hip_runtime.h>
#include <hip/hip_bf16.h>

// RNNModule: leaky ReLU RNN scan + output projection, MI355X (gfx950).
// r17: r12 scan with SWAPPED MFMA operand roles (A=w_rec frag, B=h frag).
//      breg staging and h-tile reads are byte-identical to r12; the D-fragment
//      mapping transposes to (n=16tt+4qq+r, b=lr), making each lane's 4
//      r-values contiguous in n -> epilogue shrinks to 4x f32x4 NT stores and
//      4x ds_write_b64 (was 16 scalar stores + 16 ds_write_b16). Drive prepass
//      repacked to the new per-lane element order. Proj/mask unchanged (both
//      at HBM roofline as separate kernels).

typedef __attribute__((ext_vector_type(4))) float f32x4;
typedef __attribute__((ext_vector_type(8))) short s16x8;
typedef __attribute__((ext_vector_type(2))) unsigned u32x2;

constexpr int BB = 256, TT = 750, NN = 512, INN = 6, OUTN = 2, MLEN = 250;
constexpr int BBLK = 16;                 // batch rows per block
constexpr int NBLKS = BB / BBLK;         // 16 blocks, one per CU
constexpr int WPB = 8;                   // waves per block
constexpr int NSL = NN / WPB;            // 64 neurons per wave
constexpr int NREG = 46;                 // B-frags in registers (f=0..45)
constexpr int NLDSF = 18;                // B-frags in LDS (f=46..63)
constexpr int HBYTES = BBLK * NN * 2;    // 16 KB h tile (bf16, swizzled)
constexpr int WOFF = HBYTES;             // weights region start
constexpr int SMEM_BYTES = WOFF + WPB * NLDSF * 1024;  // 163840 B = 160 KB
constexpr int DRVELTS = NBLKS * WPB * 64 * 16;         // shorts per time step

__device__ __forceinline__ unsigned short f2bf(float f) {
    unsigned v = __float_as_uint(f);
    v += 0x7fffu + ((v >> 16) & 1u);     // RNE
    return (unsigned short)(v >> 16);
}
__device__ __forceinline__ float bf2f(unsigned short h) {
    return __uint_as_float(((unsigned)h) << 16);
}

// ---- pre-pass: drv[t][blk][wave][lane][16] bf16 = noise + u @ w_in^T ----
// element e = tt*4 + r maps to (b = blk*16 + lr, n = 64w + 16tt + 4qq + r)
__global__ __launch_bounds__(256)
void drive_kernel(const float* __restrict__ u, const float* __restrict__ noise,
                  const float* __restrict__ w_in, unsigned short* __restrict__ drv)
{
    int gid = blockIdx.x * 256 + threadIdx.x;
    int t = gid >> 13;                           // 16 blk * 8 w * 64 lanes = 8192
    if (t >= TT - 1) return;
    int lane = gid & 63, w = (gid >> 6) & 7, blk = (gid >> 9) & 15;
    int qq = lane >> 4, lr = lane & 15;
    int b = blk * BBLK + lr;

    float uv[INN];
    const float* up = u + ((size_t)b * TT + t) * INN;
    #pragma unroll
    for (int i = 0; i < INN; ++i) uv[i] = up[i];

    const float* np = noise + ((size_t)b * TT + t) * NN;
    alignas(16) unsigned short o[16];
    #pragma unroll
    for (int tt = 0; tt < 4; ++tt) {
        const int n0 = w * NSL + 16 * tt + 4 * qq;
        f32x4 nz = *(const f32x4*)(np + n0);
        #pragma unroll
        for (int r = 0; r < 4; ++r) {
            float d = nz[r];
            const float* wi = w_in + (n0 + r) * INN;
            #pragma unroll
            for (int i = 0; i < INN; ++i) d += uv[i] * wi[i];
            o[tt * 4 + r] = f2bf(d);
        }
    }
    s16x8* dst = (s16x8*)(drv + (size_t)gid * 16);
    dst[0] = *(const s16x8*)&o[0];
    dst[1] = *(const s16x8*)&o[8];
}

// ---- persistent scan: 16 blocks x 8 waves, LDS-only h exchange ----
__global__ __launch_bounds__(512, 2)
void rnn_scan_kernel(const float* __restrict__ w_rec,
                     const unsigned short* __restrict__ drv,
                     float* __restrict__ states)
{
    extern __shared__ char smem[];
    const int tid = threadIdx.x;
    const int w = tid >> 6, lane = tid & 63;
    const int qq = lane >> 4, lr = lane & 15, p7 = lr & 7;
    const int blk = blockIdx.x;
    const int bg = blk * BBLK;

    // stage weights (A-operand): frag f=tt*16+kk: lane holds
    // w_rec[n=64w+16tt+lr][32kk+8qq+j]. f<46 -> regs; f>=46 -> LDS slot f-46
    s16x8 breg[NREG];
    #pragma unroll
    for (int tt = 0; tt < 4; ++tt) {
        #pragma unroll
        for (int kk = 0; kk < 16; ++kk) {
            const int f = tt * 16 + kk;
            const int n = w * NSL + 16 * tt + lr;
            const float* p = w_rec + (size_t)n * NN + 32 * kk + 8 * qq;
            f32x4 x0 = *(const f32x4*)p;
            f32x4 x1 = *(const f32x4*)(p + 4);
            union { s16x8 v; unsigned short s[8]; } fr;
            #pragma unroll
            for (int j = 0; j < 4; ++j) { fr.s[j] = f2bf(x0[j]); fr.s[4+j] = f2bf(x1[j]); }
            if (f < NREG) breg[f] = fr.v;
            else *(s16x8*)(smem + WOFF + (w * NLDSF + (f - NREG)) * 1024 + lane * 16) = fr.v;
        }
    }
    // zero h buffer (h_0 = 0) and states[:,0,:] for our rows
    for (int i = tid; i < HBYTES / 4; i += 512) ((unsigned*)smem)[i] = 0u;
    for (int i = tid; i < BBLK * NN; i += 512)
        states[(size_t)(bg + (i >> 9)) * TT * NN + (i & 511)] = 0.f;
    __syncthreads();

    float stl[16];
    #pragma unroll
    for (int i = 0; i < 16; ++i) stl[i] = 0.f;

    // h-read (B-operand) folded bases: addr(kk) = lr*1024 + ((4kk+qq)^p7)<<4
    //   = base(E/O) + 64kk   (identical to r12)
    const int rb64 = (p7 & 4) << 4;
    const int hbase0 = lr * 1024 + ((qq ^ (p7 & 3)) << 4);
    const char* hbE = smem + hbase0 + rb64;
    const char* hbO = smem + hbase0 - rb64;
    const char* wbase = smem + WOFF + w * (NLDSF * 1024) + lane * 16;

    // h-write (b64) base: addr(tt) = lr*1024 + (((8w+(qq>>1)+2tt)^(lr&7))<<4)
    //                                + 8*(qq&1)
    const int s2 = 8 * w + (qq >> 1);
    const unsigned LB2 = (unsigned)(lr * 1024 + 8 * (qq & 1));

    // states row pointer: b = bg + lr fixed; n offsets 16tt+4qq constant
    float* sp = states + ((size_t)(bg + lr) * TT + 1) * NN + w * NSL;

    const unsigned short* dptr = drv + ((size_t)(blk * WPB + w) * 64 + lane) * 16;

    for (int s = 1; s < TT; ++s) {
        // depth-0 drive load: consumed ~2500 cyc later in the epilogue
        const s16x8* dp = (const s16x8*)dptr;
        s16x8 dv0 = dp[0], dv1 = dp[1];
        dptr += DRVELTS;

        f32x4 a0 = {0.f,0.f,0.f,0.f}, a1 = a0, a2 = a0, a3 = a0;
        #pragma unroll
        for (int kk = 0; kk < 16; ++kk) {
            s16x8 hv = *(const s16x8*)(((kk & 1) ? hbO : hbE) + (kk << 6));
            a0 = __builtin_amdgcn_mfma_f32_16x16x32_bf16(breg[kk],      hv, a0, 0,0,0);
            a1 = __builtin_amdgcn_mfma_f32_16x16x32_bf16(breg[16 + kk], hv, a1, 0,0,0);
            if (kk < 14)
                a2 = __builtin_amdgcn_mfma_f32_16x16x32_bf16(breg[32+kk], hv, a2, 0,0,0);
            else
                a2 = __builtin_amdgcn_mfma_f32_16x16x32_bf16(
                         *(const s16x8*)(wbase + ((kk - 14) << 10)), hv, a2, 0, 0, 0);
            a3 = __builtin_amdgcn_mfma_f32_16x16x32_bf16(
                     *(const s16x8*)(wbase + ((2 + kk) << 10)), hv, a3, 0, 0, 0);
        }

        // ---- epilogue: D maps (n = 64w+16tt+4qq+r, b = bg+lr): per tt the 4
        //      r-values are contiguous in n -> f32x4 NT store + packed b64 ----
        union { s16x8 v; unsigned short e[8]; } U0, U1;
        U0.v = dv0; U1.v = dv1;
        const f32x4 aX[4] = {a0, a1, a2, a3};
        unsigned pk[8];
        #pragma unroll
        for (int tt = 0; tt < 4; ++tt) {
            float h_[4];
            #pragma unroll
            for (int r = 0; r < 4; ++r) {
                float d = bf2f(tt < 2 ? U0.e[tt * 4 + r] : U1.e[(tt - 2) * 4 + r]);
                float pre = aX[tt][r] + d;
                float hn = 0.8f * stl[tt * 4 + r] + 0.2f * fmaxf(pre, 0.f);
                stl[tt * 4 + r] = hn;
                h_[r] = hn;
            }
            f32x4 hv4 = {h_[0], h_[1], h_[2], h_[3]};
            __builtin_nontemporal_store(hv4, (f32x4*)(sp + 16 * tt + 4 * qq));
            __hip_bfloat162 p01 = __float22bfloat162_rn(make_float2(h_[0], h_[1]));
            __hip_bfloat162 p23 = __float22bfloat162_rn(make_float2(h_[2], h_[3]));
            pk[2 * tt]     = *reinterpret_cast<unsigned*>(&p01);
            pk[2 * tt + 1] = *reinterpret_cast<unsigned*>(&p23);
        }
        sp += NN;

        // barrier 1: all waves' h-reads drained -> safe to overwrite h
        asm volatile("s_waitcnt lgkmcnt(0)\n\ts_barrier" ::: "memory");

        #pragma unroll
        for (int tt = 0; tt < 4; ++tt) {
            const unsigned ad = LB2 + (unsigned)((((s2 + 2 * tt) ^ p7)) << 4);
            u32x2 wv = {pk[2 * tt], pk[2 * tt + 1]};
            *(u32x2*)(smem + ad) = wv;
        }
        // barrier 2: h writes visible -> next step may read
        asm volatile("s_waitcnt lgkmcnt(0)\n\ts_barrier" ::: "memory");
    }
}

// out[b,t,o] = sum_n states[b,t,n] * w_out[o,n]; one wave per (b,t) row
__global__ __launch_bounds__(256)
void proj_kernel(const float* __restrict__ states, const float* __restrict__ w_out,
                 float* __restrict__ outf)
{
    const int wv   = (blockIdx.x * blockDim.x + threadIdx.x) >> 6;
    const int lane = threadIdx.x & 63;
    const float* sp = states + (size_t)wv * NN + lane * 8;
    const float* w0 = w_out + lane * 8;
    const float* w1 = w_out + NN + lane * 8;
    float d0 = 0.f, d1 = 0.f;
    #pragma unroll
    for (int i = 0; i < 8; ++i) {
        float sv = sp[i];
        d0 += sv * w0[i];
        d1 += sv * w1[i];
    }
    #pragma unroll
    for (int off = 32; off > 0; off >>= 1) {
        d0 += __shfl_xor(d0, off);
        d1 += __shfl_xor(d1, off);
    }
    if (lane == 0) {
        outf[(size_t)wv * 2]     = d0;
        outf[(size_t)wv * 2 + 1] = d1;
    }
}

__global__ void mask_kernel(const int* __restrict__ mask, const float* __restrict__ outf,
                            float* __restrict__ outm)
{
    int idx = blockIdx.x * blockDim.x + threadIdx.x;
    if (idx >= BB * MLEN * OUTN) return;
    int o  = idx % OUTN;
    int jm = (idx / OUTN) % MLEN;
    int b  = idx / (OUTN * MLEN);
    int t  = mask[jm];
    outm[idx] = outf[((size_t)b * TT + t) * OUTN + o];
}

extern "C" void kernel_launch(void* const* d_in, const int* in_sizes, int n_in,
                              void* d_out, int out_size, void* d_ws, size_t ws_size,
                              hipStream_t stream)
{
    (void)in_sizes; (void)n_in; (void)out_size; (void)ws_size;
    const float* u     = (const float*)d_in[0];
    const float* noise = (const float*)d_in[1];
    const float* w_rec = (const float*)d_in[2];
    const float* w_in  = (const float*)d_in[3];
    const float* w_out = (const float*)d_in[4];
    const int*   mask  = (const int*)d_in[5];

    float* states = (float*)d_out;                          // [256][750][512]
    float* outm   = states + (size_t)BB * TT * NN;          // [256][250][2]
    float* outf   = outm + (size_t)BB * MLEN * OUTN;        // [256][750][2]

    unsigned short* drvpk = (unsigned short*)d_ws;          // 196.3 MB packed drive

    (void)hipFuncSetAttribute((const void*)rnn_scan_kernel,
                              hipFuncAttributeMaxDynamicSharedMemorySize, SMEM_BYTES);

    drive_kernel<<<(TT - 1) * 32, 256, 0, stream>>>(u, noise, w_in, drvpk);
    rnn_scan_kernel<<<NBLKS, 512, SMEM_BYTES, stream>>>(w_rec, drvpk, states);
    proj_kernel<<<(BB * TT) / 4, 256, 0, stream>>>(states, w_out, outf);
    mask_kernel<<<(BB * MLEN * OUTN + 255) / 256, 256, 0, stream>>>(mask, outf, outm);
}

// Round 18
// 1832.089 us; speedup vs baseline: 1.2447x; 1.0735x over previous
//
#include <hip/hip_runtime.h>
#include <hip/hip_bf16.h>

// RNNModule: leaky ReLU RNN scan + output projection, MI355X (gfx950).
// r18 = r12 champion restored (best verified: total 1833us, scan 1641us).
//      Spill-free register budget: 8 waves x 256 unified regs/wave; breg 46
//      frags (184 regs) + ~70 working <= 256. 18 B-frags/wave in LDS;
//      LDS = 16KB h (single buffer, XOR-swizzled) + 144KB weights = 160KB.
//      Two lgkm-only barriers/step; folded A-read/h-write addressing;
//      epilogue compute + NT stores before barrier 1; b16 h-writes after.
//      drive/proj/mask kernels all at HBM roofline.

typedef __attribute__((ext_vector_type(4))) float f32x4;
typedef __attribute__((ext_vector_type(8))) short s16x8;

constexpr int BB = 256, TT = 750, NN = 512, INN = 6, OUTN = 2, MLEN = 250;
constexpr int BBLK = 16;                 // batch rows per block
constexpr int NBLKS = BB / BBLK;         // 16 blocks, one per CU
constexpr int WPB = 8;                   // waves per block
constexpr int NSL = NN / WPB;            // 64 neurons per wave
constexpr int NREG = 46;                 // B-frags in registers (f=0..45)
constexpr int NLDSF = 18;                // B-frags in LDS (f=46..63)
constexpr int HBYTES = BBLK * NN * 2;    // 16 KB h tile (bf16, swizzled)
constexpr int WOFF = HBYTES;             // weights region start
constexpr int SMEM_BYTES = WOFF + WPB * NLDSF * 1024;  // 163840 B = 160 KB
constexpr int DRVELTS = NBLKS * WPB * 64 * 16;         // shorts per time step

__device__ __forceinline__ unsigned short f2bf(float f) {
    unsigned v = __float_as_uint(f);
    v += 0x7fffu + ((v >> 16) & 1u);     // RNE
    return (unsigned short)(v >> 16);
}
__device__ __forceinline__ float bf2f(unsigned short h) {
    return __uint_as_float(((unsigned)h) << 16);
}

// ---- pre-pass: drv[t][blk][wave][lane][16] bf16 = noise + u @ w_in^T ----
__global__ __launch_bounds__(256)
void drive_kernel(const float* __restrict__ u, const float* __restrict__ noise,
                  const float* __restrict__ w_in, unsigned short* __restrict__ drv)
{
    int gid = blockIdx.x * 256 + threadIdx.x;
    int t = gid >> 13;                           // 16 blk * 8 w * 64 lanes = 8192
    if (t >= TT - 1) return;
    int lane = gid & 63, w = (gid >> 6) & 7, blk = (gid >> 9) & 15;
    int qq = lane >> 4, lr = lane & 15;

    float wv[4][INN];
    #pragma unroll
    for (int tt = 0; tt < 4; ++tt) {
        int n = w * NSL + 16 * tt + lr;
        #pragma unroll
        for (int i = 0; i < INN; ++i) wv[tt][i] = w_in[n * INN + i];
    }
    alignas(16) unsigned short o[16];
    #pragma unroll
    for (int r = 0; r < 4; ++r) {
        int b = blk * BBLK + 4 * qq + r;
        const float* up = u + ((size_t)b * TT + t) * INN;
        float uv[INN];
        #pragma unroll
        for (int i = 0; i < INN; ++i) uv[i] = up[i];
        const float* np = noise + ((size_t)b * TT + t) * NN;
        #pragma unroll
        for (int tt = 0; tt < 4; ++tt) {
            int n = w * NSL + 16 * tt + lr;
            float d = np[n];
            #pragma unroll
            for (int i = 0; i < INN; ++i) d += uv[i] * wv[tt][i];
            o[tt * 4 + r] = f2bf(d);
        }
    }
    s16x8* dst = (s16x8*)(drv + (size_t)gid * 16);
    dst[0] = *(const s16x8*)&o[0];
    dst[1] = *(const s16x8*)&o[8];
}

// ---- persistent scan: 16 blocks x 8 waves, LDS-only h exchange ----
__global__ __launch_bounds__(512, 2)
void rnn_scan_kernel(const float* __restrict__ w_rec,
                     const unsigned short* __restrict__ drv,
                     float* __restrict__ states)
{
    extern __shared__ char smem[];
    const int tid = threadIdx.x;
    const int w = tid >> 6, lane = tid & 63;
    const int qq = lane >> 4, lr = lane & 15, p7 = lr & 7;
    const int blk = blockIdx.x;
    const int bg = blk * BBLK;

    // stage weights: frag f=tt*16+kk: lane holds w_rec[n=64w+16tt+lr][32kk+8qq+j]
    // f < 46 -> registers (tt0,tt1,tt2:kk0-13); f >= 46 -> LDS slot f-46
    // (tt2:kk14,15 -> slots 0,1; tt3:kk -> slot 2+kk)
    s16x8 breg[NREG];
    #pragma unroll
    for (int tt = 0; tt < 4; ++tt) {
        #pragma unroll
        for (int kk = 0; kk < 16; ++kk) {
            const int f = tt * 16 + kk;
            const int n = w * NSL + 16 * tt + lr;
            const float* p = w_rec + (size_t)n * NN + 32 * kk + 8 * qq;
            f32x4 x0 = *(const f32x4*)p;
            f32x4 x1 = *(const f32x4*)(p + 4);
            union { s16x8 v; unsigned short s[8]; } fr;
            #pragma unroll
            for (int j = 0; j < 4; ++j) { fr.s[j] = f2bf(x0[j]); fr.s[4+j] = f2bf(x1[j]); }
            if (f < NREG) breg[f] = fr.v;
            else *(s16x8*)(smem + WOFF + (w * NLDSF + (f - NREG)) * 1024 + lane * 16) = fr.v;
        }
    }
    // zero h buffer (h_0 = 0) and states[:,0,:] for our rows
    for (int i = tid; i < HBYTES / 4; i += 512) ((unsigned*)smem)[i] = 0u;
    for (int i = tid; i < BBLK * NN; i += 512)
        states[(size_t)(bg + (i >> 9)) * TT * NN + (i & 511)] = 0.f;
    __syncthreads();

    float stl[16];
    #pragma unroll
    for (int i = 0; i < 16; ++i) stl[i] = 0.f;

    // A-read folded bases: addr(kk) = lr*1024 + ((4kk+qq)^p7)<<4 = base(E/O) + 64kk
    const int rb64 = (p7 & 4) << 4;
    const int hbase0 = lr * 1024 + ((qq ^ (p7 & 3)) << 4);
    const char* hbE = smem + hbase0 + rb64;
    const char* hbO = smem + hbase0 - rb64;
    const char* wbase = smem + WOFF + w * (NLDSF * 1024) + lane * 16;

    // h-write folded base: addr(tt,r) = (LB ^ (((2tt)^r)<<4)) + 1024r
    const int s0 = 8 * w + (lr >> 3);
    const unsigned LB = 4096u * qq + ((unsigned)(s0 ^ (4 * (qq & 1))) << 4) + 2 * (lr & 7);

    float* rowp[4];
    #pragma unroll
    for (int r = 0; r < 4; ++r)
        rowp[r] = states + ((size_t)(bg + 4 * qq + r) * TT + 1) * NN + w * NSL + lr;

    const unsigned short* dptr = drv + ((size_t)(blk * WPB + w) * 64 + lane) * 16;

    for (int s = 1; s < TT; ++s) {
        // depth-0 drive load: consumed ~2500 cyc later in the epilogue
        const s16x8* dp = (const s16x8*)dptr;
        s16x8 dv0 = dp[0], dv1 = dp[1];
        dptr += DRVELTS;

        f32x4 a0 = {0.f,0.f,0.f,0.f}, a1 = a0, a2 = a0, a3 = a0;
        #pragma unroll
        for (int kk = 0; kk < 16; ++kk) {
            s16x8 av = *(const s16x8*)(((kk & 1) ? hbO : hbE) + (kk << 6));
            a0 = __builtin_amdgcn_mfma_f32_16x16x32_bf16(av, breg[kk],      a0, 0,0,0);
            a1 = __builtin_amdgcn_mfma_f32_16x16x32_bf16(av, breg[16 + kk], a1, 0,0,0);
            if (kk < 14)
                a2 = __builtin_amdgcn_mfma_f32_16x16x32_bf16(av, breg[32+kk], a2, 0,0,0);
            else
                a2 = __builtin_amdgcn_mfma_f32_16x16x32_bf16(
                         av, *(const s16x8*)(wbase + ((kk - 14) << 10)), a2, 0, 0, 0);
            a3 = __builtin_amdgcn_mfma_f32_16x16x32_bf16(
                     av, *(const s16x8*)(wbase + ((2 + kk) << 10)), a3, 0, 0, 0);
        }

        // ---- epilogue compute BEFORE the read-drain barrier (overlaps other
        //      waves' MFMA); only the LDS h-writes must wait for the barrier ----
        union { s16x8 v; unsigned short e[8]; } U0, U1;
        U0.v = dv0; U1.v = dv1;
        const f32x4 aX[4] = {a0, a1, a2, a3};
        float hnv[4][4];
        #pragma unroll
        for (int tt = 0; tt < 4; ++tt) {
            #pragma unroll
            for (int r = 0; r < 4; ++r) {
                float d = bf2f(tt < 2 ? U0.e[tt * 4 + r] : U1.e[(tt - 2) * 4 + r]);
                float pre = aX[tt][r] + d;
                float hn = 0.8f * stl[tt * 4 + r] + 0.2f * fmaxf(pre, 0.f);
                stl[tt * 4 + r] = hn;
                hnv[tt][r] = hn;
                __builtin_nontemporal_store(hn, rowp[r] + tt * 16);
            }
        }
        // pack pairs (tt even, tt odd) with one RNE cvt_pk each
        unsigned pk[8];
        #pragma unroll
        for (int p = 0; p < 2; ++p)
            #pragma unroll
            for (int r = 0; r < 4; ++r) {
                __hip_bfloat162 h2 = __float22bfloat162_rn(
                    make_float2(hnv[2 * p][r], hnv[2 * p + 1][r]));
                pk[p * 4 + r] = *reinterpret_cast<unsigned*>(&h2);
            }
        #pragma unroll
        for (int r = 0; r < 4; ++r) rowp[r] += NN;

        // barrier 1: all waves' A-reads drained -> safe to overwrite h
        asm volatile("s_waitcnt lgkmcnt(0)\n\ts_barrier" ::: "memory");

        #pragma unroll
        for (int tt = 0; tt < 4; ++tt) {
            #pragma unroll
            for (int r = 0; r < 4; ++r) {
                const unsigned C = (unsigned)(((2 * tt) ^ r) << 4);
                unsigned short hv = (tt & 1) ? (unsigned short)(pk[(tt >> 1) * 4 + r] >> 16)
                                             : (unsigned short)(pk[(tt >> 1) * 4 + r]);
                *(unsigned short*)(smem + ((LB ^ C) + 1024 * r)) = hv;
            }
        }
        // barrier 2: h writes visible -> next step may read
        asm volatile("s_waitcnt lgkmcnt(0)\n\ts_barrier" ::: "memory");
    }
}

// out[b,t,o] = sum_n states[b,t,n] * w_out[o,n]; one wave per (b,t) row
__global__ __launch_bounds__(256)
void proj_kernel(const float* __restrict__ states, const float* __restrict__ w_out,
                 float* __restrict__ outf)
{
    const int wv   = (blockIdx.x * blockDim.x + threadIdx.x) >> 6;
    const int lane = threadIdx.x & 63;
    const float* sp = states + (size_t)wv * NN + lane * 8;
    const float* w0 = w_out + lane * 8;
    const float* w1 = w_out + NN + lane * 8;
    float d0 = 0.f, d1 = 0.f;
    #pragma unroll
    for (int i = 0; i < 8; ++i) {
        float sv = sp[i];
        d0 += sv * w0[i];
        d1 += sv * w1[i];
    }
    #pragma unroll
    for (int off = 32; off > 0; off >>= 1) {
        d0 += __shfl_xor(d0, off);
        d1 += __shfl_xor(d1, off);
    }
    if (lane == 0) {
        outf[(size_t)wv * 2]     = d0;
        outf[(size_t)wv * 2 + 1] = d1;
    }
}

__global__ void mask_kernel(const int* __restrict__ mask, const float* __restrict__ outf,
                            float* __restrict__ outm)
{
    int idx = blockIdx.x * blockDim.x + threadIdx.x;
    if (idx >= BB * MLEN * OUTN) return;
    int o  = idx % OUTN;
    int jm = (idx / OUTN) % MLEN;
    int b  = idx / (OUTN * MLEN);
    int t  = mask[jm];
    outm[idx] = outf[((size_t)b * TT + t) * OUTN + o];
}

extern "C" void kernel_launch(void* const* d_in, const int* in_sizes, int n_in,
                              void* d_out, int out_size, void* d_ws, size_t ws_size,
                              hipStream_t stream)
{
    (void)in_sizes; (void)n_in; (void)out_size; (void)ws_size;
    const float* u     = (const float*)d_in[0];
    const float* noise = (const float*)d_in[1];
    const float* w_rec = (const float*)d_in[2];
    const float* w_in  = (const float*)d_in[3];
    const float* w_out = (const float*)d_in[4];
    const int*   mask  = (const int*)d_in[5];

    float* states = (float*)d_out;                          // [256][750][512]
    float* outm   = states + (size_t)BB * TT * NN;          // [256][250][2]
    float* outf   = outm + (size_t)BB * MLEN * OUTN;        // [256][750][2]

    unsigned short* drvpk = (unsigned short*)d_ws;          // 196.3 MB packed drive

    (void)hipFuncSetAttribute((const void*)rnn_scan_kernel,
                              hipFuncAttributeMaxDynamicSharedMemorySize, SMEM_BYTES);

    drive_kernel<<<(TT - 1) * 32, 256, 0, stream>>>(u, noise, w_in, drvpk);
    rnn_scan_kernel<<<NBLKS, 512, SMEM_BYTES, stream>>>(w_rec, drvpk, states);
    proj_kernel<<<(BB * TT) / 4, 256, 0, stream>>>(states, w_out, outf);
    mask_kernel<<<(BB * MLEN * OUTN + 255) / 256, 256, 0, stream>>>(mask, outf, outm);
}